// Round 3
// baseline (38.231 us; speedup 1.0000x reference)
//
#include <hip/hip_runtime.h>

// YOLO decode + register-resident bitonic sort + box-level greedy NMS.
// One block (1024 threads) per batch item. S=7,B=2,C=20 -> 98 boxes, 1960 entries.

constexpr int S_  = 7;
constexpr int Cc  = 20;
constexpr int NBOX  = 98;
constexpr int NENT  = 1960;
constexpr int NPAD  = 2048;
constexpr int LPRED = 1470;
constexpr int BATCH = 16;
constexpr float IOU_THR_  = 0.1f;
constexpr float PROB_THR_ = 8e-25f;

__device__ __forceinline__ unsigned long long
cmpsel(unsigned long long mine, unsigned long long part, int idx, int js, int k)
{
    const bool desc  = ((idx & k) == 0);
    const bool lower = ((idx & js) == 0);
    const bool keep_max = (lower == desc);
    const unsigned long long mx = mine > part ? mine : part;
    const unsigned long long mn = mine > part ? part : mine;
    return keep_max ? mx : mn;
}

__global__ __launch_bounds__(1024)
void yolo_nms_kernel(const float* __restrict__ pred_all, float* __restrict__ out)
{
    const int b   = blockIdx.x;
    const int tid = threadIdx.x;
    const int wid = tid >> 6, lane = tid & 63;
    const float* pred = pred_all + b * LPRED;

    __shared__ float s_pred[LPRED];
    __shared__ unsigned long long s_buf[2][NPAD];     // double-buffered sort exchange
    __shared__ float bXh[NBOX], bXl[NBOX], bYh[NBOX], bYl[NBOX], bA[NBOX];
    __shared__ float4 bBox[NBOX];
    __shared__ int   bCls[NBOX];
    __shared__ unsigned long long iouRow[NBOX * 2];
    __shared__ int firstpos[NBOX];
    __shared__ int boxorder[NBOX];
    __shared__ int kept[NBOX];
    __shared__ int s_nvalid;

    // ---- stage prediction + init ----
    for (int i = tid; i < LPRED; i += 1024) s_pred[i] = pred[i];
    if (tid == 0) s_nvalid = 0;
    if (tid < NBOX) { kept[tid] = 0; firstpos[tid] = 0x7FFFFFFF; }
    __syncthreads();

    // ---- decode 98 boxes (reference float32 op order) + first-class-over-thr ----
    if (tid < NBOX) {
        const int bo = tid, cell = bo >> 1;
        const int ci = cell / S_, cj = cell % S_;
        const float bx = s_pred[1078 + bo * 4 + 0];
        const float by = s_pred[1078 + bo * 4 + 1];
        const float bw = s_pred[1078 + bo * 4 + 2];
        const float bh = s_pred[1078 + bo * 4 + 3];
        const float x = (bx + (float)ci) / 7.0f * 448.0f;
        const float y = (by + (float)cj) / 7.0f * 448.0f;
        const float w = bw * bw * 448.0f;
        const float h = bh * bh * 448.0f;
        bBox[bo] = make_float4(x, y, w, h);
        bXh[bo] = x + 0.5f * w;  bXl[bo] = x - 0.5f * w;
        bYh[bo] = y + 0.5f * h;  bYl[bo] = y - 0.5f * h;
        bA[bo]  = w * h;
        const float conf = s_pred[980 + bo];
        int cls = 0;
        for (int c = 0; c < Cc; ++c)
            if (s_pred[cell * Cc + c] * conf >= PROB_THR_) { cls = c; break; }
        bCls[bo] = cls;
    }

    // ---- build sort keys directly into registers ----
    // key = (prob_bits << 32) | (0xFFFFFFFF - idx); pads = 0 (sort last).
    auto makekey = [&](int e) -> unsigned long long {
        if (e >= NENT) return 0ull;
        const int bo = e / Cc, c = e - bo * Cc, cell = bo >> 1;
        const float ep = s_pred[cell * Cc + c] * s_pred[980 + bo];
        unsigned long long key = (unsigned long long)(0xFFFFFFFFu - (unsigned)e);
        if (ep >= PROB_THR_)
            key |= ((unsigned long long)__float_as_uint(ep) << 32);
        return key;
    };
    __syncthreads();                     // decode + s_pred ready for all
    unsigned long long A  = makekey(tid);
    unsigned long long Bv = makekey(tid + 1024);

    // ---- pairwise IoU rows via ballot (no atomics, no init) ----
    for (int r = wid; r < NBOX; r += 16) {
        const float rXh = bXh[r], rXl = bXl[r], rYh = bYh[r], rYl = bYl[r], rA = bA[r];
        bool s1 = false, s2 = false;
        {
            const int j = lane;
            if (j < NBOX) {
                const float tb = fminf(rXh, bXh[j]) - fmaxf(rXl, bXl[j]);
                const float lr = fminf(rYh, bYh[j]) - fmaxf(rYl, bYl[j]);
                const float inter = (tb < 0.0f || lr < 0.0f) ? 0.0f : tb * lr;
                const float iou = inter / (rA + bA[j] - inter);
                s1 = (iou > IOU_THR_);
            }
        }
        {
            const int j = lane + 64;
            if (j < NBOX) {
                const float tb = fminf(rXh, bXh[j]) - fmaxf(rXl, bXl[j]);
                const float lr = fminf(rYh, bYh[j]) - fmaxf(rYl, bYl[j]);
                const float inter = (tb < 0.0f || lr < 0.0f) ? 0.0f : tb * lr;
                const float iou = inter / (rA + bA[j] - inter);
                s2 = (iou > IOU_THR_);
            }
        }
        const unsigned long long m1 = __ballot(s1);
        const unsigned long long m2 = __ballot(s2);
        if (lane == 0) { iouRow[r * 2] = m1; iouRow[r * 2 + 1] = m2; }
    }

    // ---- bitonic sort (descending; key ties impossible): registers + shuffles,
    //      LDS only for strides 64..512 (14 passes, 1 barrier each, double-buffered)
    int pbuf = 0;
    for (int k = 2; k <= NPAD; k <<= 1) {
        for (int js = k >> 1; js > 0; js >>= 1) {
            if (js == 1024) {                       // in-thread (k=2048: all desc)
                const unsigned long long mx = A > Bv ? A : Bv;
                const unsigned long long mn = A > Bv ? Bv : A;
                A = mx; Bv = mn;
            } else if (js >= 64) {                  // cross-wave via LDS
                s_buf[pbuf][tid]        = A;
                s_buf[pbuf][tid + 1024] = Bv;
                __syncthreads();
                const unsigned long long pA = s_buf[pbuf][tid ^ js];
                const unsigned long long pB = s_buf[pbuf][(tid + 1024) ^ js];
                A  = cmpsel(A,  pA, tid,        js, k);
                Bv = cmpsel(Bv, pB, tid + 1024, js, k);
                pbuf ^= 1;
            } else {                                // intra-wave via shuffle
                const unsigned long long pA = __shfl_xor(A,  js);
                const unsigned long long pB = __shfl_xor(Bv, js);
                A  = cmpsel(A,  pA, tid,        js, k);
                Bv = cmpsel(Bv, pB, tid + 1024, js, k);
            }
        }
    }

    // ---- commit sorted keys + per-box first position (atomicMin from regs) ----
    unsigned long long* s_k = s_buf[0];
    s_k[tid]        = A;
    s_k[tid + 1024] = Bv;
    if (A >> 32)
        atomicMin(&firstpos[(int)(0xFFFFFFFFu - (unsigned)A) / Cc], tid);
    if (Bv >> 32)
        atomicMin(&firstpos[(int)(0xFFFFFFFFu - (unsigned)Bv) / Cc], tid + 1024);
    __syncthreads();

    // ---- rank boxes by firstpos ----
    if (tid < NBOX) {
        const int fp = firstpos[tid];
        if (fp != 0x7FFFFFFF) {
            int r = 0;
            for (int b2 = 0; b2 < NBOX; ++b2) r += (firstpos[b2] < fp) ? 1 : 0;
            boxorder[r] = tid;
            atomicAdd(&s_nvalid, 1);
        }
    }
    __syncthreads();

    // ---- serial greedy keep (<=98 iterations, thread 0) ----
    if (tid == 0) {
        unsigned long long sup0 = 0ull, sup1 = 0ull;
        const int nv = s_nvalid;
        for (int r = 0; r < nv; ++r) {
            const int bb = boxorder[r];
            const unsigned long long r0 = iouRow[bb * 2];
            const unsigned long long r1 = iouRow[bb * 2 + 1];
            const bool supd = (bb < 64) ? ((sup0 >> bb) & 1ull)
                                        : ((sup1 >> (bb - 64)) & 1ull);
            if (!supd) { kept[bb] = 1; sup0 |= r0; sup1 |= r1; }
        }
    }
    __syncthreads();

    // ---- write outputs: boxes (B,N,4) | probs (B,N) | cls (B,N) ----
    float* outBoxes = out + b * (NENT * 4);
    float* outProbs = out + BATCH * NENT * 4 + b * NENT;
    float* outCls   = out + BATCH * NENT * 5 + b * NENT;
    for (int kp = tid; kp < NENT; kp += 1024) {
        const unsigned long long key = s_k[kp];
        const unsigned pb2 = (unsigned)(key >> 32);
        const int idx = (int)(0xFFFFFFFFu - (unsigned)key);
        const int bo  = idx / Cc;
        *reinterpret_cast<float4*>(outBoxes + kp * 4) = bBox[bo];
        outProbs[kp] = (pb2 != 0u && kp == firstpos[bo] && kept[bo])
                         ? __uint_as_float(pb2) : 0.0f;
        outCls[kp] = (float)bCls[bo];
    }
}

extern "C" void kernel_launch(void* const* d_in, const int* in_sizes, int n_in,
                              void* d_out, int out_size, void* d_ws, size_t ws_size,
                              hipStream_t stream)
{
    const float* pred = (const float*)d_in[0];
    float* out = (float*)d_out;
    yolo_nms_kernel<<<BATCH, 1024, 0, stream>>>(pred, out);
}

// Round 4
// 36.076 us; speedup vs baseline: 1.0597x; 1.0597x over previous
//
#include <hip/hip_runtime.h>

// YOLO decode + LDS bitonic sort (wave-local barrier elision) + wave-parallel
// greedy NMS. One block (1024 threads) per batch item.
// S=7, B=2, C=20 -> 49 cells, 98 boxes, 1960 entries.

constexpr int S_  = 7;
constexpr int Cc  = 20;
constexpr int NBOX  = 98;
constexpr int NENT  = 1960;
constexpr int NPAD  = 2048;
constexpr int LPRED = 1470;
constexpr int BATCH = 16;
constexpr float IOU_THR_  = 0.1f;
constexpr float PROB_THR_ = 8e-25f;

__device__ __forceinline__ unsigned long long rl64(unsigned long long v, int l)
{
    unsigned lo = (unsigned)__builtin_amdgcn_readlane((int)(unsigned)v, l);
    unsigned hi = (unsigned)__builtin_amdgcn_readlane((int)(unsigned)(v >> 32), l);
    return ((unsigned long long)hi << 32) | lo;
}

__global__ __launch_bounds__(1024)
void yolo_nms_kernel(const float* __restrict__ pred_all, float* __restrict__ out)
{
    const int b    = blockIdx.x;
    const int tid  = threadIdx.x;
    const int wid  = tid >> 6, lane = tid & 63;
    const float* pred = pred_all + b * LPRED;

    __shared__ float s_pred[LPRED];
    __shared__ unsigned long long s_k[NPAD];        // (prob_bits<<32)|(0xFFFFFFFF-idx)
    __shared__ float bXh[NBOX], bXl[NBOX], bYh[NBOX], bYl[NBOX], bA[NBOX];
    __shared__ float4 bBox[NBOX];
    __shared__ int   bCls[NBOX];
    __shared__ unsigned long long iouRow[NBOX * 2];
    __shared__ int firstpos[NBOX];
    __shared__ int boxorder[NBOX];
    __shared__ int kept[NBOX];
    __shared__ int s_nvalid;

    // ---- stage prediction + init ----
    for (int i = tid; i < LPRED; i += 1024) s_pred[i] = pred[i];
    if (tid == 0) s_nvalid = 0;
    if (tid < NBOX) { kept[tid] = 0; firstpos[tid] = 0x7FFFFFFF; }
    __syncthreads();

    // ---- decode 98 boxes (reference float32 op order) + first-class-over-thr ----
    if (tid < NBOX) {
        const int bo = tid, cell = bo >> 1;
        const int ci = cell / S_, cj = cell % S_;
        const float bx = s_pred[1078 + bo * 4 + 0];
        const float by = s_pred[1078 + bo * 4 + 1];
        const float bw = s_pred[1078 + bo * 4 + 2];
        const float bh = s_pred[1078 + bo * 4 + 3];
        const float x = (bx + (float)ci) / 7.0f * 448.0f;
        const float y = (by + (float)cj) / 7.0f * 448.0f;
        const float w = bw * bw * 448.0f;
        const float h = bh * bh * 448.0f;
        bBox[bo] = make_float4(x, y, w, h);
        bXh[bo] = x + 0.5f * w;  bXl[bo] = x - 0.5f * w;
        bYh[bo] = y + 0.5f * h;  bYl[bo] = y - 0.5f * h;
        bA[bo]  = w * h;
        const float conf = s_pred[980 + bo];
        int cls = 0;
        for (int c = 0; c < Cc; ++c)
            if (s_pred[cell * Cc + c] * conf >= PROB_THR_) { cls = c; break; }
        bCls[bo] = cls;
    }

    // ---- sort keys straight into LDS (thread t owns e = t and t+1024) ----
    for (int e = tid; e < NPAD; e += 1024) {
        unsigned long long key = 0ull;
        if (e < NENT) {
            const int bo = e / Cc, c = e - bo * Cc, cell = bo >> 1;
            const float ep = s_pred[cell * Cc + c] * s_pred[980 + bo];
            key = (unsigned long long)(0xFFFFFFFFu - (unsigned)e);
            if (ep >= PROB_THR_)
                key |= ((unsigned long long)__float_as_uint(ep) << 32);
        }
        s_k[e] = key;
    }
    __syncthreads();

    // ---- pairwise IoU rows via ballot (overlaps with sort start; read later) ----
    for (int r = wid; r < NBOX; r += 16) {
        const float rXh = bXh[r], rXl = bXl[r], rYh = bYh[r], rYl = bYl[r], rA = bA[r];
        bool s1 = false, s2 = false;
        {
            const int j = lane;
            const float tb = fminf(rXh, bXh[j]) - fmaxf(rXl, bXl[j]);
            const float lr = fminf(rYh, bYh[j]) - fmaxf(rYl, bYl[j]);
            const float inter = (tb < 0.0f || lr < 0.0f) ? 0.0f : tb * lr;
            const float iou = inter / (rA + bA[j] - inter);   // 0/0 -> NaN -> false
            s1 = (iou > IOU_THR_);
        }
        if (lane + 64 < NBOX) {
            const int j = lane + 64;
            const float tb = fminf(rXh, bXh[j]) - fmaxf(rXl, bXl[j]);
            const float lr = fminf(rYh, bYh[j]) - fmaxf(rYl, bYl[j]);
            const float inter = (tb < 0.0f || lr < 0.0f) ? 0.0f : tb * lr;
            const float iou = inter / (rA + bA[j] - inter);
            s2 = (iou > IOU_THR_);
        }
        const unsigned long long m1 = __ballot(s1);
        const unsigned long long m2 = __ballot(s2);
        if (lane == 0) { iouRow[r * 2] = m1; iouRow[r * 2 + 1] = m2; }
    }

    // ---- bitonic sort, descending; js<=64 passes are wave-local (no barrier:
    //      pair (idx, idx|js) stays in wave-owned chunk [128w, 128w+128)) ----
    for (int k = 2; k <= NPAD; k <<= 1) {
        for (int js = k >> 1; js > 0; js >>= 1) {
            if (js >= 128) __syncthreads();
            const int idx = ((tid & ~(js - 1)) << 1) | (tid & (js - 1));
            const int l   = idx | js;
            const unsigned long long a = s_k[idx], c = s_k[l];
            const bool dir = ((idx & k) == 0);
            if ((a < c) == dir) { s_k[idx] = c; s_k[l] = a; }
            if (js == 128) __syncthreads();
            else if (js < 128) asm volatile("s_waitcnt lgkmcnt(0)" ::: "memory");
        }
    }
    __syncthreads();

    // ---- first positive-prob sorted position per box ----
    for (int kp = tid; kp < NENT; kp += 1024) {
        const unsigned long long key = s_k[kp];
        if (key >> 32)
            atomicMin(&firstpos[(int)(0xFFFFFFFFu - (unsigned)key) / Cc], kp);
    }
    __syncthreads();

    // ---- rank boxes by firstpos (distinct -> permutation) ----
    if (tid < NBOX) {
        const int fp = firstpos[tid];
        if (fp != 0x7FFFFFFF) {
            int r = 0;
            for (int b2 = 0; b2 < NBOX; ++b2) r += (firstpos[b2] < fp) ? 1 : 0;
            boxorder[r] = tid;
            atomicAdd(&s_nvalid, 1);
        }
    }
    __syncthreads();

    // ---- greedy keep, wave-parallel: lane r holds rank-r data in VGPRs,
    //      serial decisions broadcast via readlane (SALU-speed, no LDS chain) ----
    if (tid < 64) {
        const int nv = s_nvalid;
        int bb0 = -1, bb1 = -1;
        unsigned long long r00 = 0, r01 = 0, r10 = 0, r11 = 0;
        if (tid < nv) {
            bb0 = boxorder[tid];
            r00 = iouRow[bb0 * 2]; r01 = iouRow[bb0 * 2 + 1];
        }
        if (tid + 64 < nv) {
            bb1 = boxorder[tid + 64];
            r10 = iouRow[bb1 * 2]; r11 = iouRow[bb1 * 2 + 1];
        }
        unsigned long long sup0 = 0, sup1 = 0, k0 = 0, k1 = 0;
        for (int r = 0; r < nv; ++r) {
            int bb; unsigned long long rw0, rw1;
            if (r < 64) {
                bb  = __builtin_amdgcn_readlane(bb0, r);
                rw0 = rl64(r00, r); rw1 = rl64(r01, r);
            } else {
                bb  = __builtin_amdgcn_readlane(bb1, r - 64);
                rw0 = rl64(r10, r - 64); rw1 = rl64(r11, r - 64);
            }
            const bool supped = (bb < 64) ? ((sup0 >> bb) & 1ull)
                                          : ((sup1 >> (bb - 64)) & 1ull);
            if (!supped) {
                if (bb < 64) k0 |= 1ull << bb; else k1 |= 1ull << (bb - 64);
                sup0 |= rw0; sup1 |= rw1;
            }
        }
        kept[tid] = (int)((k0 >> tid) & 1ull);
        if (tid < NBOX - 64) kept[tid + 64] = (int)((k1 >> tid) & 1ull);
    }
    __syncthreads();

    // ---- write outputs: boxes (B,N,4) | probs (B,N) | cls (B,N) ----
    float* outBoxes = out + b * (NENT * 4);
    float* outProbs = out + BATCH * NENT * 4 + b * NENT;
    float* outCls   = out + BATCH * NENT * 5 + b * NENT;
    for (int kp = tid; kp < NENT; kp += 1024) {
        const unsigned long long key = s_k[kp];
        const unsigned pb2 = (unsigned)(key >> 32);
        const int idx = (int)(0xFFFFFFFFu - (unsigned)key);
        const int bo  = idx / Cc;
        *reinterpret_cast<float4*>(outBoxes + kp * 4) = bBox[bo];
        outProbs[kp] = (pb2 != 0u && kp == firstpos[bo] && kept[bo])
                         ? __uint_as_float(pb2) : 0.0f;
        outCls[kp] = (float)bCls[bo];
    }
}

extern "C" void kernel_launch(void* const* d_in, const int* in_sizes, int n_in,
                              void* d_out, int out_size, void* d_ws, size_t ws_size,
                              hipStream_t stream)
{
    const float* pred = (const float*)d_in[0];
    float* out = (float*)d_out;
    yolo_nms_kernel<<<BATCH, 1024, 0, stream>>>(pred, out);
}